// Round 6
// baseline (182.667 us; speedup 1.0000x reference)
//
#include <hip/hip_runtime.h>
#include <hip/hip_bf16.h>
#include <math.h>

// GNNAngle round 6: SPLIT kernels for attribution + streaming decoupling.
// phase_a: pure stream. grid-stride, one wave per node, no barriers:
//   2KB load -> in-register Gram (1 MFMA) -> fast_acos -> per-wave LDS
//   transpose (256B) -> coalesced 256B feats store (f16[128], tail zero).
// phase_b: feats -> padded LDS -> 3-layer MFMA MLP -> 128->1 sigmoid.

#define NTHREADS  256
#define CHUNK     32    // nodes per phase_b block
#define ASTRIDE   136   // f16 act row stride (b128 conflict-free in MLP)

typedef _Float16 f16;
typedef f16  f16x8 __attribute__((ext_vector_type(8)));
typedef f16  f16x4 __attribute__((ext_vector_type(4)));
typedef float f32x4 __attribute__((ext_vector_type(4)));

__device__ __forceinline__ float fast_tanh(float x) {
    float e = __expf(2.0f * x);
    return 1.0f - 2.0f * __builtin_amdgcn_rcpf(e + 1.0f);
}

__device__ __forceinline__ float fast_acos(float x) {
    // Abramowitz-Stegun 4.4.45: max abs error 6.7e-5 rad, branchless
    float ax = fabsf(x);
    float p = fmaf(-0.0187293f, ax, 0.0742610f);
    p = fmaf(p, ax, -0.2121144f);
    p = fmaf(p, ax, 1.5707288f);
    float r = sqrtf(1.0f - ax) * p;
    return (x >= 0.0f) ? r : (3.14159265358979f - r);
}

// ---- prep: W[i][j] (f32 [IN][128]) -> Wt[j][i] f16 [128][128], K zero-padded
__global__ void prep_weights(const float* __restrict__ W1,
                             const float* __restrict__ W2,
                             const float* __restrict__ W3,
                             f16* __restrict__ wt)
{
    int tid = blockIdx.x * 256 + threadIdx.x;
    if (tid >= 3 * 128 * 128) return;
    int layer = tid >> 14;
    int rem   = tid & 16383;
    int j     = rem >> 7;
    int i     = rem & 127;
    const float* W = (layer == 0) ? W1 : ((layer == 1) ? W2 : W3);
    int in_l = (layer == 0) ? 120 : 128;
    float v = (i < in_l) ? W[i * 128 + j] : 0.0f;
    wt[tid] = (f16)v;   // wt[layer][j][i]
}

// ---------------- phase A: edge_attr -> feats (f16 [node][128]) ----------------
__global__ __launch_bounds__(NTHREADS, 8)
void phase_a(const float* __restrict__ edge_attr,
             f16* __restrict__ feats,
             int n_nodes, int iters, int stride_nodes)
{
    __shared__ __attribute__((aligned(16))) f16 wbuf[4 * 128];  // per-wave 256B
    const int t  = threadIdx.x;
    const int w  = t >> 6;
    const int l  = t & 63;
    const int lr = l & 15;
    const int lg = l >> 4;
    f16* wlds = wbuf + w * 128;

    long node = (long)blockIdx.x * 4 + w;
    float4 c0 = make_float4(0.f, 0.f, 0.f, 0.f), c1 = c0;
    if (node < n_nodes) {
        const float* s = edge_attr + node * 512 + lr * 32 + lg * 8;
        c0 = *(const float4*)(s);
        c1 = *(const float4*)(s + 4);
    }
    for (int it = 0; it < iters; ++it) {
        const long nx = node + stride_nodes;
        float4 n0 = make_float4(0.f, 0.f, 0.f, 0.f), n1 = n0;
        if (it + 1 < iters && nx < n_nodes) {
            const float* s = edge_attr + nx * 512 + lr * 32 + lg * 8;
            n0 = *(const float4*)(s);
            n1 = *(const float4*)(s + 4);
        }
        if (node < n_nodes) {   // wave-uniform
            float ss = c0.x*c0.x + c0.y*c0.y + c0.z*c0.z + c0.w*c0.w
                     + c1.x*c1.x + c1.y*c1.y + c1.z*c1.z + c1.w*c1.w;
            ss += __shfl_xor(ss, 16);
            ss += __shfl_xor(ss, 32);             // row (lr) norm across lg lanes
            const float sc = __builtin_amdgcn_rsqf(ss + 1e-24f);
            f16x8 frag;
            frag[0] = (f16)(c0.x * sc); frag[1] = (f16)(c0.y * sc);
            frag[2] = (f16)(c0.z * sc); frag[3] = (f16)(c0.w * sc);
            frag[4] = (f16)(c1.x * sc); frag[5] = (f16)(c1.y * sc);
            frag[6] = (f16)(c1.z * sc); frag[7] = (f16)(c1.w * sc);
            f32x4 acc = {0.f, 0.f, 0.f, 0.f};
            acc = __builtin_amdgcn_mfma_f32_16x16x32_f16(frag, frag, acc, 0, 0, 0);
            if (l < 8) wlds[120 + l] = (f16)0.f;  // K-pad 120..127
            const int col = lr;
            #pragma unroll
            for (int r2 = 0; r2 < 4; ++r2) {
                const int row = lg * 4 + r2;
                float c = fminf(fmaxf(acc[r2], -1.0f + 1e-7f), 1.0f - 1e-7f);
                float ang = fast_acos(c);
                if (row < col) {
                    const int p = 15 * row - ((row * (row - 1)) >> 1) + (col - row - 1);
                    wlds[p] = (f16)ang;
                }
            }
            // wave-internal LDS visibility, then coalesced 256B store
            asm volatile("s_waitcnt lgkmcnt(0)" ::: "memory");
            __builtin_amdgcn_sched_barrier(0);
            ((unsigned int*)(feats + node * 128))[l] = ((const unsigned int*)wlds)[l];
        }
        node = nx; c0 = n0; c1 = n1;
    }
}

// ---------------- phase B: feats -> MLP -> out ----------------
__device__ __forceinline__ void mlp_layer_mfma(const f16* __restrict__ wl,   // [128][128] f16 ([j][i])
                                               const float* __restrict__ bias,
                                               const f16* src, f16* dst,     // LDS, stride ASTRIDE
                                               int w, int lr, int lg)
{
    #pragma unroll
    for (int jj = 0; jj < 2; ++jj) {
        const int jt = w * 2 + jj;
        const f16* wr = wl + (jt * 16 + lr) * 128 + lg * 8;
        f16x8 a0 = *(const f16x8*)(wr);
        f16x8 a1 = *(const f16x8*)(wr + 32);
        f16x8 a2 = *(const f16x8*)(wr + 64);
        f16x8 a3 = *(const f16x8*)(wr + 96);
        f32x4 bv = *(const f32x4*)(bias + jt * 16 + lg * 4);
        #pragma unroll
        for (int nt = 0; nt < 2; ++nt) {
            const int node = nt * 16 + lr;
            const f16* sr = src + node * ASTRIDE + lg * 8;
            f16x8 bf0 = *(const f16x8*)(sr);
            f16x8 bf1 = *(const f16x8*)(sr + 32);
            f16x8 bf2 = *(const f16x8*)(sr + 64);
            f16x8 bf3 = *(const f16x8*)(sr + 96);
            f32x4 acc = {0.f, 0.f, 0.f, 0.f};
            acc = __builtin_amdgcn_mfma_f32_16x16x32_f16(a0, bf0, acc, 0, 0, 0);
            acc = __builtin_amdgcn_mfma_f32_16x16x32_f16(a1, bf1, acc, 0, 0, 0);
            acc = __builtin_amdgcn_mfma_f32_16x16x32_f16(a2, bf2, acc, 0, 0, 0);
            acc = __builtin_amdgcn_mfma_f32_16x16x32_f16(a3, bf3, acc, 0, 0, 0);
            f16x4 o;
            #pragma unroll
            for (int r = 0; r < 4; ++r)
                o[r] = (f16)fast_tanh(acc[r] + bv[r]);
            *(f16x4*)(dst + node * ASTRIDE + jt * 16 + lg * 4) = o;
        }
    }
}

__global__ __launch_bounds__(NTHREADS, 8)
void phase_b(const f16* __restrict__ feats,
             const f16* __restrict__ wt,
             const float* __restrict__ b1, const float* __restrict__ b2,
             const float* __restrict__ b3,
             const float* __restrict__ W4, const float* __restrict__ b4,
             float* __restrict__ out, int n_nodes)
{
    __shared__ __attribute__((aligned(16))) f16 actA[CHUNK * ASTRIDE];
    __shared__ __attribute__((aligned(16))) f16 actB[CHUNK * ASTRIDE];

    const int t = threadIdx.x;
    const int w = t >> 6;    // wave 0..3
    const int l = t & 63;
    const int base = blockIdx.x * CHUNK;
    const int lr = l & 15;
    const int lg = l >> 4;

    // stage feats (32 nodes x 256B = 8KB) into padded LDS
    {
        const int m = t >> 3, part = t & 7;
        const long g = (long)base + m;
        f16x8 v0 = {}; f16x8 v1 = {};
        if (g < n_nodes) {
            const f16* s = feats + g * 128 + part * 16;
            v0 = *(const f16x8*)(s);
            v1 = *(const f16x8*)(s + 8);
        }
        *(f16x8*)(actA + m * ASTRIDE + part * 16)     = v0;
        *(f16x8*)(actA + m * ASTRIDE + part * 16 + 8) = v1;
    }
    __syncthreads();

    mlp_layer_mfma(wt,             b1, actA, actB, w, lr, lg);
    __syncthreads();
    mlp_layer_mfma(wt + 16384,     b2, actB, actA, w, lr, lg);
    __syncthreads();
    mlp_layer_mfma(wt + 2 * 16384, b3, actA, actB, w, lr, lg);
    __syncthreads();

    // final 128->1 + sigmoid: 8 threads per node
    {
        const int node = t >> 3;
        const int part = t & 7;
        const int i0 = part * 16;
        const f16* sr = actB + node * ASTRIDE + i0;
        f16x8 h0 = *(const f16x8*)(sr);
        f16x8 h1 = *(const f16x8*)(sr + 8);
        float s = 0.f;
        #pragma unroll
        for (int e = 0; e < 8; ++e) s = fmaf((float)h0[e], W4[i0 + e], s);
        #pragma unroll
        for (int e = 0; e < 8; ++e) s = fmaf((float)h1[e], W4[i0 + 8 + e], s);
        s += __shfl_xor(s, 1);
        s += __shfl_xor(s, 2);
        s += __shfl_xor(s, 4);
        if (part == 0) {
            const long g = (long)base + node;
            if (g < n_nodes)
                out[g] = __builtin_amdgcn_rcpf(1.0f + __expf(-(s + b4[0])));
        }
    }
}

extern "C" void kernel_launch(void* const* d_in, const int* in_sizes, int n_in,
                              void* d_out, int out_size, void* d_ws, size_t ws_size,
                              hipStream_t stream) {
    // inputs: 0:x 1:edge_index 2:edge_attr 3:k 4:W1 5:b1 6:W2 7:b2 8:W3 9:b3 10:W4 11:b4
    const float* edge_attr = (const float*)d_in[2];
    const float* W1 = (const float*)d_in[4];
    const float* b1 = (const float*)d_in[5];
    const float* W2 = (const float*)d_in[6];
    const float* b2 = (const float*)d_in[7];
    const float* W3 = (const float*)d_in[8];
    const float* b3 = (const float*)d_in[9];
    const float* W4 = (const float*)d_in[10];
    const float* b4 = (const float*)d_in[11];
    float* out = (float*)d_out;

    f16* wt    = (f16*)d_ws;                               // 96 KB
    f16* feats = (f16*)((char*)d_ws + 3 * 128 * 128 * 2);  // N*128 f16 = 51.2 MB

    const int n_nodes = in_sizes[2] / 512;                 // E*D / (16*32)

    prep_weights<<<(3 * 128 * 128 + 255) / 256, 256, 0, stream>>>(W1, W2, W3, wt);

    const int ablocks = 2048;
    const int stride_nodes = ablocks * 4;                  // waves per grid pass
    const int iters = (n_nodes + stride_nodes - 1) / stride_nodes;
    phase_a<<<ablocks, NTHREADS, 0, stream>>>(edge_attr, feats, n_nodes, iters, stride_nodes);

    const int bblocks = (n_nodes + CHUNK - 1) / CHUNK;
    phase_b<<<bblocks, NTHREADS, 0, stream>>>(feats, wt, b1, b2, b3, W4, b4, out, n_nodes);
}

// Round 7
// 153.291 us; speedup vs baseline: 1.1916x; 1.1916x over previous
//
#include <hip/hip_runtime.h>
#include <hip/hip_bf16.h>
#include <math.h>

// GNNAngle round 7: fused again (split regressed), with COALESCED phase-A loads.
// Old loads: lane offsets lr*32+lg*8 floats -> 16B-on/16B-off pattern, 2x the
// VMEM transactions (kernel was transaction-bound at ~3.3 TB/s). New: lane l
// loads float4 at 4l and 4l+256 (two contiguous 1KB segments), then per-wave
// LDS stage ([16][40] f16, 80B row stride) rearranges into the MFMA fragment.

#define CHUNK     32    // nodes per block
#define NTHREADS  256   // 4 waves
#define ASTRIDE   136   // f16 act row stride (b128 conflict-free in MLP)
#define VSTRIDE   40    // f16 stride of the per-wave [16][VSTRIDE] staging tile

typedef _Float16 f16;
typedef f16  f16x8 __attribute__((ext_vector_type(8)));
typedef f16  f16x4 __attribute__((ext_vector_type(4)));
typedef float f32x4 __attribute__((ext_vector_type(4)));

__device__ __forceinline__ float fast_tanh(float x) {
    float e = __expf(2.0f * x);
    return 1.0f - 2.0f * __builtin_amdgcn_rcpf(e + 1.0f);
}

__device__ __forceinline__ float fast_acos(float x) {
    // Abramowitz-Stegun 4.4.45: max abs error 6.7e-5 rad, branchless
    float ax = fabsf(x);
    float p = fmaf(-0.0187293f, ax, 0.0742610f);
    p = fmaf(p, ax, -0.2121144f);
    p = fmaf(p, ax, 1.5707288f);
    float r = sqrtf(1.0f - ax) * p;
    return (x >= 0.0f) ? r : (3.14159265358979f - r);
}

// ---- prep: W[i][j] (f32 [IN][128]) -> Wt[j][i] f16 [128][128], K zero-padded
__global__ void prep_weights(const float* __restrict__ W1,
                             const float* __restrict__ W2,
                             const float* __restrict__ W3,
                             f16* __restrict__ wt)
{
    int tid = blockIdx.x * 256 + threadIdx.x;
    if (tid >= 3 * 128 * 128) return;
    int layer = tid >> 14;
    int rem   = tid & 16383;
    int j     = rem >> 7;
    int i     = rem & 127;
    const float* W = (layer == 0) ? W1 : ((layer == 1) ? W2 : W3);
    int in_l = (layer == 0) ? 120 : 128;
    float v = (i < in_l) ? W[i * 128 + j] : 0.0f;
    wt[tid] = (f16)v;   // wt[layer][j][i]
}

// one MLP layer: dst[node][j] = tanh(sum_i src[node][i]*W[i][j] + b[j])
__device__ __forceinline__ void mlp_layer_mfma(const f16* __restrict__ wl,   // [128][128] f16 ([j][i])
                                               const float* __restrict__ bias,
                                               const f16* src, f16* dst,     // LDS, stride ASTRIDE
                                               int w, int lr, int lg)
{
    #pragma unroll
    for (int jj = 0; jj < 2; ++jj) {
        const int jt = w * 2 + jj;
        const f16* wr = wl + (jt * 16 + lr) * 128 + lg * 8;
        f16x8 a0 = *(const f16x8*)(wr);
        f16x8 a1 = *(const f16x8*)(wr + 32);
        f16x8 a2 = *(const f16x8*)(wr + 64);
        f16x8 a3 = *(const f16x8*)(wr + 96);
        f32x4 bv = *(const f32x4*)(bias + jt * 16 + lg * 4);
        #pragma unroll
        for (int nt = 0; nt < 2; ++nt) {
            const int node = nt * 16 + lr;
            const f16* sr = src + node * ASTRIDE + lg * 8;
            f16x8 bf0 = *(const f16x8*)(sr);
            f16x8 bf1 = *(const f16x8*)(sr + 32);
            f16x8 bf2 = *(const f16x8*)(sr + 64);
            f16x8 bf3 = *(const f16x8*)(sr + 96);
            f32x4 acc = {0.f, 0.f, 0.f, 0.f};
            acc = __builtin_amdgcn_mfma_f32_16x16x32_f16(a0, bf0, acc, 0, 0, 0);
            acc = __builtin_amdgcn_mfma_f32_16x16x32_f16(a1, bf1, acc, 0, 0, 0);
            acc = __builtin_amdgcn_mfma_f32_16x16x32_f16(a2, bf2, acc, 0, 0, 0);
            acc = __builtin_amdgcn_mfma_f32_16x16x32_f16(a3, bf3, acc, 0, 0, 0);
            f16x4 o;
            #pragma unroll
            for (int r = 0; r < 4; ++r)
                o[r] = (f16)fast_tanh(acc[r] + bv[r]);
            *(f16x4*)(dst + node * ASTRIDE + jt * 16 + lg * 4) = o;
        }
    }
}

__global__ __launch_bounds__(NTHREADS, 8)
void gnn_angle_fused(const float* __restrict__ edge_attr,
                     const f16*   __restrict__ wt,     // 3x[128][128] f16
                     const float* __restrict__ b1, const float* __restrict__ b2,
                     const float* __restrict__ b3,
                     const float* __restrict__ W4, const float* __restrict__ b4,
                     float* __restrict__ out, int n_nodes)
{
    __shared__ __attribute__((aligned(16))) f16 actA[CHUNK * ASTRIDE];
    __shared__ __attribute__((aligned(16))) f16 actB[CHUNK * ASTRIDE]; // phase A: wave staging

    const int t = threadIdx.x;
    const int w = t >> 6;    // wave 0..3
    const int l = t & 63;
    const int base = blockIdx.x * CHUNK;
    const int lr = l & 15;
    const int lg = l >> 4;

    // per-wave staging tile [16][VSTRIDE] f16 (aliases actB, unused in phase A)
    f16* wreg = actB + w * (16 * VSTRIDE);
    const int rowA = l >> 3;          // 0..7
    const int colf = (l & 7) * 4;     // f16 col of this lane's 4-float chunk

    // ---------------- Phase A: coalesced load + LDS-stage + Gram MFMA + acos ----
    // lane l loads float4 at node*512 + 4l (bytes [16l,16l+16)) and +1024.
    const float* srcw = edge_attr + (long)(base + w) * 512 + l * 4;
    float4 c0 = make_float4(0.f, 0.f, 0.f, 0.f), c1 = c0;
    if ((long)base + w < n_nodes) {
        c0 = *(const float4*)(srcw);
        c1 = *(const float4*)(srcw + 256);
    }
    for (int it = 0; it < 8; ++it) {
        const int m = it * 4 + w;                // local node 0..31
        float4 n0 = make_float4(0.f, 0.f, 0.f, 0.f), n1 = n0;
        if (it < 7 && (long)base + m + 4 < n_nodes) {
            const float* s = srcw + (it + 1) * 4 * 512;
            n0 = *(const float4*)(s);
            n1 = *(const float4*)(s + 256);
        }
        // per-row sum of squares: rows rowA (chunk c0) and rowA+8 (chunk c1);
        // reduce over the 8 lanes sharing l>>3 (xor bits 0..2)
        float sA = c0.x*c0.x + c0.y*c0.y + c0.z*c0.z + c0.w*c0.w;
        float sB = c1.x*c1.x + c1.y*c1.y + c1.z*c1.z + c1.w*c1.w;
        sA += __shfl_xor(sA, 1); sB += __shfl_xor(sB, 1);
        sA += __shfl_xor(sA, 2); sB += __shfl_xor(sB, 2);
        sA += __shfl_xor(sA, 4); sB += __shfl_xor(sB, 4);
        const float scA = __builtin_amdgcn_rsqf(sA + 1e-24f);
        const float scB = __builtin_amdgcn_rsqf(sB + 1e-24f);
        f16x4 hA, hB;
        hA[0] = (f16)(c0.x * scA); hA[1] = (f16)(c0.y * scA);
        hA[2] = (f16)(c0.z * scA); hA[3] = (f16)(c0.w * scA);
        hB[0] = (f16)(c1.x * scB); hB[1] = (f16)(c1.y * scB);
        hB[2] = (f16)(c1.z * scB); hB[3] = (f16)(c1.w * scB);
        // stage normalized rows into [16][VSTRIDE] f16
        *(f16x4*)(wreg + rowA * VSTRIDE + colf)       = hA;
        *(f16x4*)(wreg + (rowA + 8) * VSTRIDE + colf) = hB;
        asm volatile("s_waitcnt lgkmcnt(0)" ::: "memory");
        __builtin_amdgcn_sched_barrier(0);
        // fragment read: row lr, k = lg*8..+8
        f16x8 frag = *(const f16x8*)(wreg + lr * VSTRIDE + lg * 8);
        f32x4 acc = {0.f, 0.f, 0.f, 0.f};
        acc = __builtin_amdgcn_mfma_f32_16x16x32_f16(frag, frag, acc, 0, 0, 0);
        if (l < 8) actA[m * ASTRIDE + 120 + l] = (f16)0.f;  // K-pad 120..127
        const int col = lr;
        #pragma unroll
        for (int r2 = 0; r2 < 4; ++r2) {
            const int row = lg * 4 + r2;
            float c = fminf(fmaxf(acc[r2], -1.0f + 1e-7f), 1.0f - 1e-7f);
            float ang = fast_acos(c);
            if (row < col) {
                const int p = 15 * row - ((row * (row - 1)) >> 1) + (col - row - 1);
                actA[m * ASTRIDE + p] = (f16)ang;
            }
        }
        c0 = n0; c1 = n1;
    }
    __syncthreads();   // feats done; actB (staging) free for phase B reuse

    // ---------------- Phase B: MLP on MFMA ----------------
    mlp_layer_mfma(wt,             b1, actA, actB, w, lr, lg);
    __syncthreads();
    mlp_layer_mfma(wt + 16384,     b2, actB, actA, w, lr, lg);
    __syncthreads();
    mlp_layer_mfma(wt + 2 * 16384, b3, actA, actB, w, lr, lg);
    __syncthreads();

    // ---------------- final 128->1 + sigmoid: 8 threads per node ----------------
    {
        const int node = t >> 3;       // 0..31
        const int part = t & 7;        // 0..7
        const int i0 = part * 16;
        const f16* sr = actB + node * ASTRIDE + i0;
        f16x8 h0 = *(const f16x8*)(sr);
        f16x8 h1 = *(const f16x8*)(sr + 8);
        float s = 0.f;
        #pragma unroll
        for (int e = 0; e < 8; ++e) s = fmaf((float)h0[e], W4[i0 + e], s);
        #pragma unroll
        for (int e = 0; e < 8; ++e) s = fmaf((float)h1[e], W4[i0 + 8 + e], s);
        s += __shfl_xor(s, 1);
        s += __shfl_xor(s, 2);
        s += __shfl_xor(s, 4);
        if (part == 0) {
            const long g = (long)base + node;
            if (g < n_nodes)
                out[g] = __builtin_amdgcn_rcpf(1.0f + __expf(-(s + b4[0])));
        }
    }
}

extern "C" void kernel_launch(void* const* d_in, const int* in_sizes, int n_in,
                              void* d_out, int out_size, void* d_ws, size_t ws_size,
                              hipStream_t stream) {
    // inputs: 0:x 1:edge_index 2:edge_attr 3:k 4:W1 5:b1 6:W2 7:b2 8:W3 9:b3 10:W4 11:b4
    const float* edge_attr = (const float*)d_in[2];
    const float* W1 = (const float*)d_in[4];
    const float* b1 = (const float*)d_in[5];
    const float* W2 = (const float*)d_in[6];
    const float* b2 = (const float*)d_in[7];
    const float* W3 = (const float*)d_in[8];
    const float* b3 = (const float*)d_in[9];
    const float* W4 = (const float*)d_in[10];
    const float* b4 = (const float*)d_in[11];
    float* out = (float*)d_out;
    f16* wt = (f16*)d_ws;                        // 3*128*128 f16 = 96 KB

    const int n_nodes = in_sizes[2] / 512;       // E*D / (16*32)

    prep_weights<<<(3 * 128 * 128 + 255) / 256, 256, 0, stream>>>(W1, W2, W3, wt);

    const int blocks = (n_nodes + CHUNK - 1) / CHUNK;
    gnn_angle_fused<<<blocks, NTHREADS, 0, stream>>>(
        edge_attr, wt, b1, b2, b3, W4, b4, out, n_nodes);
}

// Round 8
// 140.373 us; speedup vs baseline: 1.3013x; 1.0920x over previous
//
#include <hip/hip_runtime.h>
#include <hip/hip_bf16.h>
#include <math.h>

// GNNAngle round 8: attack wave-level pipeline depth / ILP (the one invariant
// across the R4-R7 plateau). Each wave handles 2 nodes per iteration (two
// independent chains, interleaved) with the next 2 nodes' 4 loads in flight.
// Full-block fast path: no bounds checks in the hot loop (N % 32 == 0 here).

#define CHUNK     32    // nodes per block
#define NTHREADS  256   // 4 waves
#define ASTRIDE   136   // f16 act row stride (b128 conflict-free in MLP)

typedef _Float16 f16;
typedef f16  f16x8 __attribute__((ext_vector_type(8)));
typedef f16  f16x4 __attribute__((ext_vector_type(4)));
typedef float f32x4 __attribute__((ext_vector_type(4)));

__device__ __forceinline__ float fast_tanh(float x) {
    float e = __expf(2.0f * x);
    return 1.0f - 2.0f * __builtin_amdgcn_rcpf(e + 1.0f);
}

__device__ __forceinline__ float fast_acos(float x) {
    // Abramowitz-Stegun 4.4.45: max abs error 6.7e-5 rad, branchless
    float ax = fabsf(x);
    float p = fmaf(-0.0187293f, ax, 0.0742610f);
    p = fmaf(p, ax, -0.2121144f);
    p = fmaf(p, ax, 1.5707288f);
    float r = sqrtf(1.0f - ax) * p;
    return (x >= 0.0f) ? r : (3.14159265358979f - r);
}

// ---- prep: W[i][j] (f32 [IN][128]) -> Wt[j][i] f16 [128][128], K zero-padded
__global__ void prep_weights(const float* __restrict__ W1,
                             const float* __restrict__ W2,
                             const float* __restrict__ W3,
                             f16* __restrict__ wt)
{
    int tid = blockIdx.x * 256 + threadIdx.x;
    if (tid >= 3 * 128 * 128) return;
    int layer = tid >> 14;
    int rem   = tid & 16383;
    int j     = rem >> 7;
    int i     = rem & 127;
    const float* W = (layer == 0) ? W1 : ((layer == 1) ? W2 : W3);
    int in_l = (layer == 0) ? 120 : 128;
    float v = (i < in_l) ? W[i * 128 + j] : 0.0f;
    wt[tid] = (f16)v;   // wt[layer][j][i]
}

// per-node Gram+acos: c0/c1 hold row lr, dims lg*8..+8; writes angles to actA row m
__device__ __forceinline__ void gram_acos_node(float4 c0, float4 c1, int m,
                                               int lr, int lg, f16* actA)
{
    float ss = c0.x*c0.x + c0.y*c0.y + c0.z*c0.z + c0.w*c0.w
             + c1.x*c1.x + c1.y*c1.y + c1.z*c1.z + c1.w*c1.w;
    ss += __shfl_xor(ss, 16);
    ss += __shfl_xor(ss, 32);                // row (lr) norm across the 4 lg lanes
    const float sc = __builtin_amdgcn_rsqf(ss + 1e-24f);
    f16x8 frag;
    frag[0] = (f16)(c0.x * sc); frag[1] = (f16)(c0.y * sc);
    frag[2] = (f16)(c0.z * sc); frag[3] = (f16)(c0.w * sc);
    frag[4] = (f16)(c1.x * sc); frag[5] = (f16)(c1.y * sc);
    frag[6] = (f16)(c1.z * sc); frag[7] = (f16)(c1.w * sc);
    f32x4 acc = {0.f, 0.f, 0.f, 0.f};
    acc = __builtin_amdgcn_mfma_f32_16x16x32_f16(frag, frag, acc, 0, 0, 0);
    const int col = lr;
    #pragma unroll
    for (int r2 = 0; r2 < 4; ++r2) {
        const int row = lg * 4 + r2;
        float c = fminf(fmaxf(acc[r2], -1.0f + 1e-7f), 1.0f - 1e-7f);
        float ang = fast_acos(c);
        if (row < col) {
            const int p = 15 * row - ((row * (row - 1)) >> 1) + (col - row - 1);
            actA[m * ASTRIDE + p] = (f16)ang;
        }
    }
}

// one MLP layer: dst[node][j] = tanh(sum_i src[node][i]*W[i][j] + b[j])
__device__ __forceinline__ void mlp_layer_mfma(const f16* __restrict__ wl,   // [128][128] f16 ([j][i])
                                               const float* __restrict__ bias,
                                               const f16* src, f16* dst,     // LDS, stride ASTRIDE
                                               int w, int lr, int lg)
{
    #pragma unroll
    for (int jj = 0; jj < 2; ++jj) {
        const int jt = w * 2 + jj;
        const f16* wr = wl + (jt * 16 + lr) * 128 + lg * 8;
        f16x8 a0 = *(const f16x8*)(wr);
        f16x8 a1 = *(const f16x8*)(wr + 32);
        f16x8 a2 = *(const f16x8*)(wr + 64);
        f16x8 a3 = *(const f16x8*)(wr + 96);
        f32x4 bv = *(const f32x4*)(bias + jt * 16 + lg * 4);
        #pragma unroll
        for (int nt = 0; nt < 2; ++nt) {
            const int node = nt * 16 + lr;
            const f16* sr = src + node * ASTRIDE + lg * 8;
            f16x8 bf0 = *(const f16x8*)(sr);
            f16x8 bf1 = *(const f16x8*)(sr + 32);
            f16x8 bf2 = *(const f16x8*)(sr + 64);
            f16x8 bf3 = *(const f16x8*)(sr + 96);
            f32x4 acc = {0.f, 0.f, 0.f, 0.f};
            acc = __builtin_amdgcn_mfma_f32_16x16x32_f16(a0, bf0, acc, 0, 0, 0);
            acc = __builtin_amdgcn_mfma_f32_16x16x32_f16(a1, bf1, acc, 0, 0, 0);
            acc = __builtin_amdgcn_mfma_f32_16x16x32_f16(a2, bf2, acc, 0, 0, 0);
            acc = __builtin_amdgcn_mfma_f32_16x16x32_f16(a3, bf3, acc, 0, 0, 0);
            f16x4 o;
            #pragma unroll
            for (int r = 0; r < 4; ++r)
                o[r] = (f16)fast_tanh(acc[r] + bv[r]);
            *(f16x4*)(dst + node * ASTRIDE + jt * 16 + lg * 4) = o;
        }
    }
}

__global__ __launch_bounds__(NTHREADS, 4)
void gnn_angle_fused(const float* __restrict__ edge_attr,
                     const f16*   __restrict__ wt,     // 3x[128][128] f16
                     const float* __restrict__ b1, const float* __restrict__ b2,
                     const float* __restrict__ b3,
                     const float* __restrict__ W4, const float* __restrict__ b4,
                     float* __restrict__ out, int n_nodes)
{
    __shared__ __attribute__((aligned(16))) f16 actA[CHUNK * ASTRIDE];
    __shared__ __attribute__((aligned(16))) f16 actB[CHUNK * ASTRIDE];

    const int t = threadIdx.x;
    const int w = t >> 6;    // wave 0..3
    const int l = t & 63;
    const int base = blockIdx.x * CHUNK;
    const int lr = l & 15;
    const int lg = l >> 4;

    // K-pad feats 120..127 for all 32 rows, once (disjoint from angle writes)
    actA[(t >> 3) * ASTRIDE + 120 + (t & 7)] = (f16)0.f;

    const float* srcw = edge_attr + (long)base * 512 + lr * 32 + lg * 8;

    if (base + CHUNK <= n_nodes) {
        // -------- fast path: full block, zero bounds checks ----------
        // wave w: iteration it handles nodes m0=it*8+w, m1=m0+4;
        // next iteration's 4 loads issued before current compute.
        float4 a0, a1, b0, b1;
        {
            const float* s0 = srcw + (long)w * 512;
            const float* s1 = srcw + (long)(w + 4) * 512;
            a0 = *(const float4*)(s0); a1 = *(const float4*)(s0 + 4);
            b0 = *(const float4*)(s1); b1 = *(const float4*)(s1 + 4);
        }
        #pragma unroll
        for (int it = 0; it < 4; ++it) {
            const int m0 = it * 8 + w;
            const int m1 = m0 + 4;
            float4 na0, na1, nb0, nb1;
            if (it < 3) {
                const float* s0 = srcw + (long)(m0 + 8) * 512;
                const float* s1 = srcw + (long)(m1 + 8) * 512;
                na0 = *(const float4*)(s0); na1 = *(const float4*)(s0 + 4);
                nb0 = *(const float4*)(s1); nb1 = *(const float4*)(s1 + 4);
            }
            // two independent chains; compiler interleaves for ILP
            gram_acos_node(a0, a1, m0, lr, lg, actA);
            gram_acos_node(b0, b1, m1, lr, lg, actA);
            if (it < 3) { a0 = na0; a1 = na1; b0 = nb0; b1 = nb1; }
        }
    } else {
        // -------- guarded tail path (rare) ----------
        for (int it = 0; it < 8; ++it) {
            const int m = it * 4 + w;
            const long g = (long)base + m;
            if (g < n_nodes) {
                const float* s = srcw + (long)m * 512;
                float4 c0 = *(const float4*)(s);
                float4 c1 = *(const float4*)(s + 4);
                gram_acos_node(c0, c1, m, lr, lg, actA);
            }
        }
    }
    __syncthreads();

    // ---------------- Phase B: MLP on MFMA ----------------
    mlp_layer_mfma(wt,             b1, actA, actB, w, lr, lg);
    __syncthreads();
    mlp_layer_mfma(wt + 16384,     b2, actB, actA, w, lr, lg);
    __syncthreads();
    mlp_layer_mfma(wt + 2 * 16384, b3, actA, actB, w, lr, lg);
    __syncthreads();

    // ---------------- final 128->1 + sigmoid: 8 threads per node ----------------
    {
        const int node = t >> 3;       // 0..31
        const int part = t & 7;        // 0..7
        const int i0 = part * 16;
        const f16* sr = actB + node * ASTRIDE + i0;
        f16x8 h0 = *(const f16x8*)(sr);
        f16x8 h1 = *(const f16x8*)(sr + 8);
        float s = 0.f;
        #pragma unroll
        for (int e = 0; e < 8; ++e) s = fmaf((float)h0[e], W4[i0 + e], s);
        #pragma unroll
        for (int e = 0; e < 8; ++e) s = fmaf((float)h1[e], W4[i0 + 8 + e], s);
        s += __shfl_xor(s, 1);
        s += __shfl_xor(s, 2);
        s += __shfl_xor(s, 4);
        if (part == 0) {
            const long g = (long)base + node;
            if (g < n_nodes)
                out[g] = __builtin_amdgcn_rcpf(1.0f + __expf(-(s + b4[0])));
        }
    }
}

extern "C" void kernel_launch(void* const* d_in, const int* in_sizes, int n_in,
                              void* d_out, int out_size, void* d_ws, size_t ws_size,
                              hipStream_t stream) {
    // inputs: 0:x 1:edge_index 2:edge_attr 3:k 4:W1 5:b1 6:W2 7:b2 8:W3 9:b3 10:W4 11:b4
    const float* edge_attr = (const float*)d_in[2];
    const float* W1 = (const float*)d_in[4];
    const float* b1 = (const float*)d_in[5];
    const float* W2 = (const float*)d_in[6];
    const float* b2 = (const float*)d_in[7];
    const float* W3 = (const float*)d_in[8];
    const float* b3 = (const float*)d_in[9];
    const float* W4 = (const float*)d_in[10];
    const float* b4 = (const float*)d_in[11];
    float* out = (float*)d_out;
    f16* wt = (f16*)d_ws;                        // 3*128*128 f16 = 96 KB

    const int n_nodes = in_sizes[2] / 512;       // E*D / (16*32)

    prep_weights<<<(3 * 128 * 128 + 255) / 256, 256, 0, stream>>>(W1, W2, W3, wt);

    const int blocks = (n_nodes + CHUNK - 1) / CHUNK;
    gnn_angle_fused<<<blocks, NTHREADS, 0, stream>>>(
        edge_attr, wt, b1, b2, b3, W4, b4, out, n_nodes);
}

// Round 9
// 138.872 us; speedup vs baseline: 1.3154x; 1.0108x over previous
//
#include <hip/hip_runtime.h>
#include <hip/hip_bf16.h>
#include <math.h>

// GNNAngle round 9: maximum per-wave memory pipeline depth. Each wave loads
// ALL 8 of its nodes (16 x dwordx4, 16 KB in flight) up front, then runs the
// 8 Gram+acos chains; compiler emits descending vmcnt waits -> one latency
// exposure per wave instead of four. launch_bounds(256,3) to avoid spills.

#define CHUNK     32    // nodes per block
#define NTHREADS  256   // 4 waves
#define ASTRIDE   136   // f16 act row stride (b128 conflict-free in MLP)

typedef _Float16 f16;
typedef f16  f16x8 __attribute__((ext_vector_type(8)));
typedef f16  f16x4 __attribute__((ext_vector_type(4)));
typedef float f32x4 __attribute__((ext_vector_type(4)));

__device__ __forceinline__ float fast_tanh(float x) {
    float e = __expf(2.0f * x);
    return 1.0f - 2.0f * __builtin_amdgcn_rcpf(e + 1.0f);
}

__device__ __forceinline__ float fast_acos(float x) {
    // Abramowitz-Stegun 4.4.45: max abs error 6.7e-5 rad, branchless
    float ax = fabsf(x);
    float p = fmaf(-0.0187293f, ax, 0.0742610f);
    p = fmaf(p, ax, -0.2121144f);
    p = fmaf(p, ax, 1.5707288f);
    float r = sqrtf(1.0f - ax) * p;
    return (x >= 0.0f) ? r : (3.14159265358979f - r);
}

// ---- prep: W[i][j] (f32 [IN][128]) -> Wt[j][i] f16 [128][128], K zero-padded
__global__ void prep_weights(const float* __restrict__ W1,
                             const float* __restrict__ W2,
                             const float* __restrict__ W3,
                             f16* __restrict__ wt)
{
    int tid = blockIdx.x * 256 + threadIdx.x;
    if (tid >= 3 * 128 * 128) return;
    int layer = tid >> 14;
    int rem   = tid & 16383;
    int j     = rem >> 7;
    int i     = rem & 127;
    const float* W = (layer == 0) ? W1 : ((layer == 1) ? W2 : W3);
    int in_l = (layer == 0) ? 120 : 128;
    float v = (i < in_l) ? W[i * 128 + j] : 0.0f;
    wt[tid] = (f16)v;   // wt[layer][j][i]
}

// per-node Gram+acos: c0/c1 hold row lr, dims lg*8..+8; writes angles to actA row m
__device__ __forceinline__ void gram_acos_node(float4 c0, float4 c1, int m,
                                               int lr, int lg, f16* actA)
{
    float ss = c0.x*c0.x + c0.y*c0.y + c0.z*c0.z + c0.w*c0.w
             + c1.x*c1.x + c1.y*c1.y + c1.z*c1.z + c1.w*c1.w;
    ss += __shfl_xor(ss, 16);
    ss += __shfl_xor(ss, 32);                // row (lr) norm across the 4 lg lanes
    const float sc = __builtin_amdgcn_rsqf(ss + 1e-24f);
    f16x8 frag;
    frag[0] = (f16)(c0.x * sc); frag[1] = (f16)(c0.y * sc);
    frag[2] = (f16)(c0.z * sc); frag[3] = (f16)(c0.w * sc);
    frag[4] = (f16)(c1.x * sc); frag[5] = (f16)(c1.y * sc);
    frag[6] = (f16)(c1.z * sc); frag[7] = (f16)(c1.w * sc);
    f32x4 acc = {0.f, 0.f, 0.f, 0.f};
    acc = __builtin_amdgcn_mfma_f32_16x16x32_f16(frag, frag, acc, 0, 0, 0);
    const int col = lr;
    #pragma unroll
    for (int r2 = 0; r2 < 4; ++r2) {
        const int row = lg * 4 + r2;
        float c = fminf(fmaxf(acc[r2], -1.0f + 1e-7f), 1.0f - 1e-7f);
        float ang = fast_acos(c);
        if (row < col) {
            const int p = 15 * row - ((row * (row - 1)) >> 1) + (col - row - 1);
            actA[m * ASTRIDE + p] = (f16)ang;
        }
    }
}

// one MLP layer: dst[node][j] = tanh(sum_i src[node][i]*W[i][j] + b[j])
__device__ __forceinline__ void mlp_layer_mfma(const f16* __restrict__ wl,   // [128][128] f16 ([j][i])
                                               const float* __restrict__ bias,
                                               const f16* src, f16* dst,     // LDS, stride ASTRIDE
                                               int w, int lr, int lg)
{
    #pragma unroll
    for (int jj = 0; jj < 2; ++jj) {
        const int jt = w * 2 + jj;
        const f16* wr = wl + (jt * 16 + lr) * 128 + lg * 8;
        f16x8 a0 = *(const f16x8*)(wr);
        f16x8 a1 = *(const f16x8*)(wr + 32);
        f16x8 a2 = *(const f16x8*)(wr + 64);
        f16x8 a3 = *(const f16x8*)(wr + 96);
        f32x4 bv = *(const f32x4*)(bias + jt * 16 + lg * 4);
        #pragma unroll
        for (int nt = 0; nt < 2; ++nt) {
            const int node = nt * 16 + lr;
            const f16* sr = src + node * ASTRIDE + lg * 8;
            f16x8 bf0 = *(const f16x8*)(sr);
            f16x8 bf1 = *(const f16x8*)(sr + 32);
            f16x8 bf2 = *(const f16x8*)(sr + 64);
            f16x8 bf3 = *(const f16x8*)(sr + 96);
            f32x4 acc = {0.f, 0.f, 0.f, 0.f};
            acc = __builtin_amdgcn_mfma_f32_16x16x32_f16(a0, bf0, acc, 0, 0, 0);
            acc = __builtin_amdgcn_mfma_f32_16x16x32_f16(a1, bf1, acc, 0, 0, 0);
            acc = __builtin_amdgcn_mfma_f32_16x16x32_f16(a2, bf2, acc, 0, 0, 0);
            acc = __builtin_amdgcn_mfma_f32_16x16x32_f16(a3, bf3, acc, 0, 0, 0);
            f16x4 o;
            #pragma unroll
            for (int r = 0; r < 4; ++r)
                o[r] = (f16)fast_tanh(acc[r] + bv[r]);
            *(f16x4*)(dst + node * ASTRIDE + jt * 16 + lg * 4) = o;
        }
    }
}

__global__ __launch_bounds__(NTHREADS, 3)
void gnn_angle_fused(const float* __restrict__ edge_attr,
                     const f16*   __restrict__ wt,     // 3x[128][128] f16
                     const float* __restrict__ b1, const float* __restrict__ b2,
                     const float* __restrict__ b3,
                     const float* __restrict__ W4, const float* __restrict__ b4,
                     float* __restrict__ out, int n_nodes)
{
    __shared__ __attribute__((aligned(16))) f16 actA[CHUNK * ASTRIDE];
    __shared__ __attribute__((aligned(16))) f16 actB[CHUNK * ASTRIDE];

    const int t = threadIdx.x;
    const int w = t >> 6;    // wave 0..3
    const int l = t & 63;
    const int base = blockIdx.x * CHUNK;
    const int lr = l & 15;
    const int lg = l >> 4;

    // K-pad feats 120..127 for all 32 rows, once (disjoint from angle writes)
    actA[(t >> 3) * ASTRIDE + 120 + (t & 7)] = (f16)0.f;

    // wave w owns nodes m = 4c + w, c = 0..7; per-node data at sw + c*2048 floats
    const float* sw = edge_attr + ((long)base + w) * 512 + lr * 32 + lg * 8;

    if (base + CHUNK <= n_nodes) {
        // -------- fast path: issue ALL 16 loads, then 8 compute chains --------
        float4 d0a = *(const float4*)(sw +     0), d0b = *(const float4*)(sw +     4);
        float4 d1a = *(const float4*)(sw +  2048), d1b = *(const float4*)(sw +  2052);
        float4 d2a = *(const float4*)(sw +  4096), d2b = *(const float4*)(sw +  4100);
        float4 d3a = *(const float4*)(sw +  6144), d3b = *(const float4*)(sw +  6148);
        float4 d4a = *(const float4*)(sw +  8192), d4b = *(const float4*)(sw +  8196);
        float4 d5a = *(const float4*)(sw + 10240), d5b = *(const float4*)(sw + 10244);
        float4 d6a = *(const float4*)(sw + 12288), d6b = *(const float4*)(sw + 12292);
        float4 d7a = *(const float4*)(sw + 14336), d7b = *(const float4*)(sw + 14340);
        gram_acos_node(d0a, d0b, w +  0, lr, lg, actA);
        gram_acos_node(d1a, d1b, w +  4, lr, lg, actA);
        gram_acos_node(d2a, d2b, w +  8, lr, lg, actA);
        gram_acos_node(d3a, d3b, w + 12, lr, lg, actA);
        gram_acos_node(d4a, d4b, w + 16, lr, lg, actA);
        gram_acos_node(d5a, d5b, w + 20, lr, lg, actA);
        gram_acos_node(d6a, d6b, w + 24, lr, lg, actA);
        gram_acos_node(d7a, d7b, w + 28, lr, lg, actA);
    } else {
        // -------- guarded tail path (rare) ----------
        for (int c = 0; c < 8; ++c) {
            const int m = c * 4 + w;
            const long g = (long)base + m;
            if (g < n_nodes) {
                const float* s = sw + (long)c * 2048;
                float4 c0 = *(const float4*)(s);
                float4 c1 = *(const float4*)(s + 4);
                gram_acos_node(c0, c1, m, lr, lg, actA);
            }
        }
    }
    __syncthreads();

    // ---------------- Phase B: MLP on MFMA ----------------
    mlp_layer_mfma(wt,             b1, actA, actB, w, lr, lg);
    __syncthreads();
    mlp_layer_mfma(wt + 16384,     b2, actB, actA, w, lr, lg);
    __syncthreads();
    mlp_layer_mfma(wt + 2 * 16384, b3, actA, actB, w, lr, lg);
    __syncthreads();

    // ---------------- final 128->1 + sigmoid: 8 threads per node ----------------
    {
        const int node = t >> 3;       // 0..31
        const int part = t & 7;        // 0..7
        const int i0 = part * 16;
        const f16* sr = actB + node * ASTRIDE + i0;
        f16x8 h0 = *(const f16x8*)(sr);
        f16x8 h1 = *(const f16x8*)(sr + 8);
        float s = 0.f;
        #pragma unroll
        for (int e = 0; e < 8; ++e) s = fmaf((float)h0[e], W4[i0 + e], s);
        #pragma unroll
        for (int e = 0; e < 8; ++e) s = fmaf((float)h1[e], W4[i0 + 8 + e], s);
        s += __shfl_xor(s, 1);
        s += __shfl_xor(s, 2);
        s += __shfl_xor(s, 4);
        if (part == 0) {
            const long g = (long)base + node;
            if (g < n_nodes)
                out[g] = __builtin_amdgcn_rcpf(1.0f + __expf(-(s + b4[0])));
        }
    }
}

extern "C" void kernel_launch(void* const* d_in, const int* in_sizes, int n_in,
                              void* d_out, int out_size, void* d_ws, size_t ws_size,
                              hipStream_t stream) {
    // inputs: 0:x 1:edge_index 2:edge_attr 3:k 4:W1 5:b1 6:W2 7:b2 8:W3 9:b3 10:W4 11:b4
    const float* edge_attr = (const float*)d_in[2];
    const float* W1 = (const float*)d_in[4];
    const float* b1 = (const float*)d_in[5];
    const float* W2 = (const float*)d_in[6];
    const float* b2 = (const float*)d_in[7];
    const float* W3 = (const float*)d_in[8];
    const float* b3 = (const float*)d_in[9];
    const float* W4 = (const float*)d_in[10];
    const float* b4 = (const float*)d_in[11];
    float* out = (float*)d_out;
    f16* wt = (f16*)d_ws;                        // 3*128*128 f16 = 96 KB

    const int n_nodes = in_sizes[2] / 512;       // E*D / (16*32)

    prep_weights<<<(3 * 128 * 128 + 255) / 256, 256, 0, stream>>>(W1, W2, W3, wt);

    const int blocks = (n_nodes + CHUNK - 1) / CHUNK;
    gnn_angle_fused<<<blocks, NTHREADS, 0, stream>>>(
        edge_attr, wt, b1, b2, b3, W4, b4, out, n_nodes);
}